// Round 10
// baseline (1193.388 us; speedup 1.0000x reference)
//
#include <hip/hip_runtime.h>

// ---------------------------------------------------------------------------
// TransformerBlock: B=2, L=2048, D=2048, H=16, HD=128, FF=8192.
// Dual-dtype (runtime-detected): DT=0 (f32 I/O — ACTIVE path per rocprof) and
// DT=1 (bf16 I/O); detector writes flag; kernels no-op unless flag==PID.
// DT=0 pre-converts each f32 weight panel to bf16 (convw_kernel) into scratch
// (d_out until the final GEMM, h2-region for the last down chunk).
// GEMMs: gemm_bt (m97-class 128x128/BKK=64, 256 thr, 32KiB LDS, 4-5 blk/CU,
// granule-XOR swizzle = 0 bank conflicts, global_load_lds both sides).
// Attention (round-10): grid 1024 (1 q-tile/block), XCD-clustered mapping
// (4 heads/XCD = 4MB K/V = per-XCD L2), gemm-pattern XOR layouts for sP and
// sVt (8-way -> 2-way banks), LDS exactly 40960 B -> 4 blocks/CU.
// Workspace (64MB + flag word): qkv[0,48) / x2[0,16) / h2[16,32) / a[32,64)
//   h,o[48,64); flag at min(64MB, ws_size-4). d_out doubles as weight scratch.
// ---------------------------------------------------------------------------

typedef __attribute__((ext_vector_type(8))) short bf16x8;
typedef __attribute__((ext_vector_type(4))) float f32x4;

__device__ __forceinline__ float b2f(unsigned short u) {
    return __uint_as_float(((unsigned int)u) << 16);
}
__device__ __forceinline__ unsigned short f2b(float f) {
    unsigned int i = __float_as_uint(f);
    i += 0x7fffu + ((i >> 16) & 1u);   // RNE
    return (unsigned short)(i >> 16);
}
// packed f32x2 -> bf16x2 (RNE), single VALU op; no builtin on gfx950
__device__ __forceinline__ unsigned int cvt_pk_bf16(float lo, float hi) {
    unsigned int r;
    asm("v_cvt_pk_bf16_f32 %0, %1, %2" : "=v"(r) : "v"(lo), "v"(hi));
    return r;
}

// async global->LDS, 16 B per lane; LDS dest is wave-uniform base + lane*16.
__device__ __forceinline__ void gload_lds16(const unsigned short* g, unsigned short* l) {
    __builtin_amdgcn_global_load_lds(
        (const __attribute__((address_space(1))) unsigned int*)g,
        (__attribute__((address_space(3))) unsigned int*)l,
        16, 0, 0);
}

// ---- typed I/O helpers: DT=1 bf16, DT=0 f32 -------------------------------
template<int DT> struct IO;
template<> struct IO<1> {
    static __device__ __forceinline__ void load8(const void* p, size_t i, float* o) {
        uint4 v = *(const uint4*)((const unsigned short*)p + i);
        const unsigned short* u = (const unsigned short*)&v;
#pragma unroll
        for (int e = 0; e < 8; e++) o[e] = b2f(u[e]);
    }
    static __device__ __forceinline__ float load1(const void* p, size_t i) {
        return b2f(((const unsigned short*)p)[i]);
    }
    static __device__ __forceinline__ void store1(void* p, size_t i, float v) {
        ((unsigned short*)p)[i] = f2b(v);
    }
};
template<> struct IO<0> {
    static __device__ __forceinline__ void load8(const void* p, size_t i, float* o) {
        float4 a = *(const float4*)((const float*)p + i);
        float4 b = *(const float4*)((const float*)p + i + 4);
        o[0]=a.x; o[1]=a.y; o[2]=a.z; o[3]=a.w;
        o[4]=b.x; o[5]=b.y; o[6]=b.z; o[7]=b.w;
    }
    static __device__ __forceinline__ float load1(const void* p, size_t i) {
        return ((const float*)p)[i];
    }
    static __device__ __forceinline__ void store1(void* p, size_t i, float v) {
        ((float*)p)[i] = v;
    }
};

// ---------------------------------------------------------------------------
// Detector: classify x's encoding. flag = 1 (bf16) / 0 (f32).
// ---------------------------------------------------------------------------
__global__ __launch_bounds__(256) void detect_kernel(
    const unsigned int* __restrict__ x, int* __restrict__ flag)
{
    const int t = threadIdx.x;
    int cnt = 0;
    for (int i = t; i < 2048; i += 256) {
        unsigned int e = (x[i] >> 7) & 0xFFu;
        cnt += (e >= 100u && e <= 140u) ? 1 : 0;
    }
#pragma unroll
    for (int off = 32; off; off >>= 1) cnt += __shfl_xor(cnt, off);
    __shared__ int red[4];
    if ((t & 63) == 0) red[t >> 6] = cnt;
    __syncthreads();
    if (t == 0) {
        int tot = red[0] + red[1] + red[2] + red[3];
        flag[0] = (2 * tot > 2048) ? 1 : 0;
    }
}

// ---------------------------------------------------------------------------
// Weight pre-convert: f32 (lds_ stride) -> bf16 (ldd stride, contiguous).
// ---------------------------------------------------------------------------
template<int PID>
__global__ __launch_bounds__(256) void convw_kernel(
    const int* __restrict__ flag,
    const float* __restrict__ S, int lds_,
    unsigned short* __restrict__ D, int ldd,
    int total)
{
    if (flag[0] != PID) return;
    const int i = (blockIdx.x * 256 + threadIdx.x) * 8;
    if (i >= total) return;
    const int row = i / ldd, col = i - row * ldd;
    const float* sp = S + (size_t)row * lds_ + col;
    float4 f0 = *(const float4*)sp;
    float4 f1 = *(const float4*)(sp + 4);
    uint4 ov;
    ov.x = cvt_pk_bf16(f0.x, f0.y);
    ov.y = cvt_pk_bf16(f0.z, f0.w);
    ov.z = cvt_pk_bf16(f1.x, f1.y);
    ov.w = cvt_pk_bf16(f1.z, f1.w);
    *(uint4*)(D + i) = ov;
}

// ---------------------------------------------------------------------------
// RMSNorm row kernel. X dtype DTX, weight DTW, output always bf16.
// ---------------------------------------------------------------------------
template<int PID, int DTX, int DTW>
__global__ __launch_bounds__(256) void rmsnorm_kernel(
    const int* __restrict__ flag,
    const void* __restrict__ X,
    const void* __restrict__ Wn,
    unsigned short* __restrict__ Out)
{
    if (flag[0] != PID) return;
    const int row = blockIdx.x, t = threadIdx.x;
    float xf[8];
    IO<DTX>::load8(X, (size_t)row * 2048 + t * 8, xf);
    float ss = 0.f;
#pragma unroll
    for (int e = 0; e < 8; e++) ss += xf[e] * xf[e];
#pragma unroll
    for (int off = 32; off; off >>= 1) ss += __shfl_xor(ss, off);
    __shared__ float red[4];
    if ((t & 63) == 0) red[t >> 6] = ss;
    __syncthreads();
    float rr = rsqrtf((red[0] + red[1] + red[2] + red[3]) * (1.0f / 2048.0f) + 1e-6f);
    float wf[8];
    IO<DTW>::load8(Wn, (size_t)t * 8, wf);
    float y[8];
#pragma unroll
    for (int e = 0; e < 8; e++) y[e] = xf[e] * rr * wf[e];
    uint4 ov;
    ov.x = cvt_pk_bf16(y[0], y[1]);
    ov.y = cvt_pk_bf16(y[2], y[3]);
    ov.z = cvt_pk_bf16(y[4], y[5]);
    ov.w = cvt_pk_bf16(y[6], y[7]);
    *(uint4*)(Out + (size_t)row * 2048 + t * 8) = ov;
}

// ---------------------------------------------------------------------------
// GEMM (m97-class, proven): C(M,N) = A(M,K)bf16 @ W(N,ldw)bf16^T [+ epilogue].
// 128x128 tile, BKK=64, 4 waves x (4x4) mfma_16x16x32_bf16 (64x64 per wave).
// EPI: 0=store, 1=+Res store, 2=silu store, 3=*Res store.
// ---------------------------------------------------------------------------
#define BM 128
#define BN 128
#define BKK 64

template<int PID, int DTR, int DTC, int EPI>
__global__ __launch_bounds__(256) void gemm_bt(
    const int* __restrict__ flag,
    const unsigned short* __restrict__ A,
    const unsigned short* __restrict__ W, size_t woff, int ldw,
    const void* __restrict__ Res,
    void* __restrict__ C,
    int N, int K)
{
    if (flag[0] != PID) return;
    __shared__ unsigned short sA[BM * BKK];
    __shared__ unsigned short sB[BN * BKK];
    const int t = threadIdx.x;
    const int bm = blockIdx.x * BM, bn = blockIdx.y * BN;
    const int w = t >> 6, lane = t & 63, quad = lane >> 4, l16 = lane & 15;
    const int wm = (w & 1) * 64, wn = (w >> 1) * 64;

    const int srow = lane >> 3;               // row within 8-row issue group
    const int sg   = (lane & 7) ^ srow;       // pre-swizzled source granule

    f32x4 acc[4][4];
#pragma unroll
    for (int mi = 0; mi < 4; mi++)
#pragma unroll
        for (int ni = 0; ni < 4; ni++) {
            f32x4 z = {0.f, 0.f, 0.f, 0.f};
            acc[mi][ni] = z;
        }

    for (int k0 = 0; k0 < K; k0 += BKK) {
        // ---- stage A + W (both bf16, async direct-to-LDS) ----
#pragma unroll
        for (int i = 0; i < 4; i++) {
            const int r0 = w * 32 + i * 8;
            gload_lds16(A + (size_t)(bm + r0 + srow) * K + k0 + sg * 8,
                        &sA[r0 * BKK]);
        }
#pragma unroll
        for (int i = 0; i < 4; i++) {
            const int r0 = w * 32 + i * 8;
            gload_lds16(W + woff + (size_t)(bn + r0 + srow) * ldw + k0 + sg * 8,
                        &sB[r0 * BKK]);
        }
        __syncthreads();   // drains vmcnt(0): LDS tiles complete

        // ---- compute: 2 k-subtiles x 16 mfma ----
#pragma unroll
        for (int ks = 0; ks < 2; ks++) {
            bf16x8 af[4], bfr[4];
#pragma unroll
            for (int mi = 0; mi < 4; mi++) {
                const int r = wm + mi * 16 + l16;
                af[mi] = *(const bf16x8*)
                    &sA[r * BKK + (((ks * 4 + quad) ^ (r & 7)) * 8)];
            }
#pragma unroll
            for (int ni = 0; ni < 4; ni++) {
                const int r = wn + ni * 16 + l16;
                bfr[ni] = *(const bf16x8*)
                    &sB[r * BKK + (((ks * 4 + quad) ^ (r & 7)) * 8)];
            }
#pragma unroll
            for (int mi = 0; mi < 4; mi++)
#pragma unroll
                for (int ni = 0; ni < 4; ni++)
                    acc[mi][ni] = __builtin_amdgcn_mfma_f32_16x16x32_bf16(
                        af[mi], bfr[ni], acc[mi][ni], 0, 0, 0);
        }
        __syncthreads();
    }

#pragma unroll
    for (int mi = 0; mi < 4; mi++)
#pragma unroll
        for (int ni = 0; ni < 4; ni++)
#pragma unroll
            for (int r = 0; r < 4; r++) {
                const int row = bm + wm + mi * 16 + quad * 4 + r;
                const int col = bn + wn + ni * 16 + l16;
                const size_t idx = (size_t)row * N + col;
                float v = acc[mi][ni][r];
                if constexpr (EPI == 1) v += IO<DTR>::load1(Res, idx);
                if constexpr (EPI == 2) v = v / (1.f + __expf(-v));
                if constexpr (EPI == 3) v *= IO<DTR>::load1(Res, idx);
                IO<DTC>::store1(C, idx, v);
            }
}

// ---------------------------------------------------------------------------
// Flash-style MFMA attention, round-10 layout.
// Grid 1024: xcd = bid&7, local = bid>>3; bh = xcd*4 + (local>>5) (4 heads
// per XCD -> K/V working set 4MB = per-XCD L2); qt = 31-(local&31) (long
// blocks first). One 64-row q-tile per block, 4 waves x 16 rows.
// LDS (40960 B total -> exactly 4 blocks/CU):
//   sK  [64][128] elem, granule-XOR within row      (16384 B)
//   sVt [128][64] elem, gemm-pattern XOR (slot = g ^ (d&7))   (16384 B)
//   sP  [4][16][64] elem, gemm-pattern XOR per wave  (8192 B)
// sVt transpose-stores use e-rotation (e = (i + (t&7))&7) so d&7 varies per
// lane -> ~4-way max; all b128 fragment reads are the proven gemm pattern
// (~2-way = free; gemm measured 0 conflicts).
// ---------------------------------------------------------------------------
template<int PID>
__global__ __launch_bounds__(256) void attn_kernel(
    const int* __restrict__ flag,
    const unsigned short* __restrict__ QKV,
    unsigned short* __restrict__ O)
{
    if (flag[0] != PID) return;
    __shared__ unsigned short sK[64 * 128];
    __shared__ unsigned short sVt[128 * 64];
    __shared__ unsigned short sP[4][16 * 64];

    const int t = threadIdx.x;
    const int xcd = blockIdx.x & 7;
    const int local = blockIdx.x >> 3;
    const int bh = xcd * 4 + (local >> 5);   // 0..31
    const int qt = 31 - (local & 31);        // 0..31, long blocks first
    const int b = bh >> 4, hh = bh & 15;
    const int w = t >> 6, lane = t & 63, quad = lane >> 4, l16 = lane & 15;

    const unsigned short* Qb = QKV + (size_t)(b * 2048) * 6144 + hh * 128;
    const unsigned short* Kb = Qb + 2048;
    const unsigned short* Vb = Qb + 4096;

    const int str = t >> 4;          // staging row (0..15), +16 per pass
    const int stc = (t & 15) * 8;    // staging col base (0..120)
    const int rot = t & 7;           // e-rotation for sVt store bank-spread

    const int qbase = qt * 64;

    // Q fragments (raw bf16). Lane holds Q[row=l16][k=ks*32+quad*8..+8]
    bf16x8 qf[4];
    {
        const unsigned short* qp = Qb + (size_t)(qbase + w * 16 + l16) * 6144;
#pragma unroll
        for (int ks = 0; ks < 4; ks++)
            qf[ks] = *(const bf16x8*)(qp + ks * 32 + quad * 8);
    }

    float m[4], l[4];
#pragma unroll
    for (int r = 0; r < 4; r++) { m[r] = -1e30f; l[r] = 0.f; }
    f32x4 accO[8];
#pragma unroll
    for (int d0 = 0; d0 < 8; d0++) {
        f32x4 z = {0.f, 0.f, 0.f, 0.f};
        accO[d0] = z;
    }

    for (int tk = 0; tk <= qt; tk++) {
        const int kv0 = tk * 64;
        __syncthreads();   // prior tile's LDS reads done before overwrite
        // ---- stage K (row-granule XOR) + V transposed (gemm-XOR layout) ----
#pragma unroll
        for (int pass = 0; pass < 4; pass++) {
            const int rr = str + pass * 16;
            uint4 kv4 = *(const uint4*)(Kb + (size_t)(kv0 + rr) * 6144 + stc);
            *(uint4*)&sK[(rr * 128 + stc) ^ ((rr & 7) << 3)] = kv4;
            uint4 vv4 = *(const uint4*)(Vb + (size_t)(kv0 + rr) * 6144 + stc);
            const unsigned short* vu = (const unsigned short*)&vv4;
#pragma unroll
            for (int i = 0; i < 8; i++) {
                const int e = (i + rot) & 7;
                const int d = stc + e;
                sVt[d * 64 + ((((rr >> 3) ^ (d & 7)) << 3) | (rr & 7))] = vu[e];
            }
        }
        __syncthreads();

        // ---- S = Q K^T ----
        const bool diag = (tk == qt);
        f32x4 s[4];
#pragma unroll
        for (int nf = 0; nf < 4; nf++) {
            f32x4 z = {0.f, 0.f, 0.f, 0.f};
            s[nf] = z;
            if (!(diag && nf > w)) {
#pragma unroll
                for (int ks = 0; ks < 4; ks++) {
                    const int row = nf * 16 + l16;
                    bf16x8 kf = *(const bf16x8*)
                        &sK[(row * 128 + ks * 32 + quad * 8) ^ ((row & 7) << 3)];
                    s[nf] = __builtin_amdgcn_mfma_f32_16x16x32_bf16(qf[ks], kf, s[nf], 0, 0, 0);
                }
            }
#pragma unroll
            for (int r = 0; r < 4; r++) s[nf][r] *= 0.08838834764831845f;
        }
        if (diag) {
#pragma unroll
            for (int nf = 0; nf < 4; nf++)
#pragma unroll
                for (int r = 0; r < 4; r++)
                    if (nf * 16 + l16 > w * 16 + quad * 4 + r) s[nf][r] = -1e30f;
        }

        // ---- online softmax (rows owned by quads; reduce over l16) ----
        float alpha[4], rs[4];
#pragma unroll
        for (int r = 0; r < 4; r++) {
            float v = fmaxf(fmaxf(s[0][r], s[1][r]), fmaxf(s[2][r], s[3][r]));
            v = fmaxf(v, __shfl_xor(v, 1));
            v = fmaxf(v, __shfl_xor(v, 2));
            v = fmaxf(v, __shfl_xor(v, 4));
            v = fmaxf(v, __shfl_xor(v, 8));
            float mn = fmaxf(m[r], v);
            alpha[r] = __expf(m[r] - mn);
            m[r] = mn;
            rs[r] = 0.f;
        }
#pragma unroll
        for (int nf = 0; nf < 4; nf++)
#pragma unroll
            for (int r = 0; r < 4; r++) {
                float p = __expf(s[nf][r] - m[r]);
                rs[r] += p;
                const int row = quad * 4 + r;
                const int g = nf * 2 + (l16 >> 3);
                sP[w][row * 64 + (((g ^ (row & 7)) << 3) | (l16 & 7))] = f2b(p);
            }
#pragma unroll
        for (int r = 0; r < 4; r++) {
            float sum = rs[r];
            sum += __shfl_xor(sum, 1);
            sum += __shfl_xor(sum, 2);
            sum += __shfl_xor(sum, 4);
            sum += __shfl_xor(sum, 8);
            l[r] = l[r] * alpha[r] + sum;
        }
#pragma unroll
        for (int d0 = 0; d0 < 8; d0++)
#pragma unroll
            for (int r = 0; r < 4; r++) accO[d0][r] *= alpha[r];

        // ---- O += P V  (A from own sP, B from sVt; same-wave LDS dep) ----
#pragma unroll
        for (int ks = 0; ks < 2; ks++) {
            bf16x8 pa = *(const bf16x8*)
                &sP[w][l16 * 64 + (((ks * 4 + quad) ^ (l16 & 7)) << 3)];
#pragma unroll
            for (int d0 = 0; d0 < 8; d0++) {
                const int row = d0 * 16 + l16;
                bf16x8 vb = *(const bf16x8*)
                    &sVt[row * 64 + (((ks * 4 + quad) ^ (l16 & 7)) << 3)];
                accO[d0] = __builtin_amdgcn_mfma_f32_16x16x32_bf16(pa, vb, accO[d0], 0, 0, 0);
            }
        }
    }

    // ---- epilogue ----
    float linv[4];
#pragma unroll
    for (int r = 0; r < 4; r++) linv[r] = 1.0f / l[r];
    unsigned short* Op = O + (size_t)(b * 2048 + qbase + w * 16) * 2048 + hh * 128;
#pragma unroll
    for (int d0 = 0; d0 < 8; d0++)
#pragma unroll
        for (int r = 0; r < 4; r++)
            Op[(size_t)(quad * 4 + r) * 2048 + d0 * 16 + l16] =
                f2b(accO[d0][r] * linv[r]);
}

// ---------------------------------------------------------------------------
template<int DT>
static void run_pipeline(const void* x, const void* n1w, const void* qkvw,
                         const void* outw, const void* n2w, const void* gatew,
                         const void* upw, const void* downw,
                         void* outp, char* ws, const int* flag, hipStream_t stream)
{
    const size_t MB = 1024 * 1024;
    unsigned short* qkv = (unsigned short*)(ws);            // [0,48)
    unsigned short* x2  = (unsigned short*)(ws);            // [0,16) after qkv dead
    unsigned short* h2  = (unsigned short*)(ws + 16 * MB);  // [16,32)
    unsigned short* a   = (unsigned short*)(ws + 32 * MB);  // [32,64)
    unsigned short* h   = (unsigned short*)(ws + 48 * MB);  // [48,64)
    unsigned short* o   = (unsigned short*)(ws + 48 * MB);  // [48,64) after h dead

    // 1) h = rmsnorm(x, w1)
    rmsnorm_kernel<DT, DT, DT><<<4096, 256, 0, stream>>>(flag, x, n1w, h);

    if constexpr (DT == 1) {
        const unsigned short* Wq = (const unsigned short*)qkvw;
        const unsigned short* Wo = (const unsigned short*)outw;
        const unsigned short* Wg = (const unsigned short*)gatew;
        const unsigned short* Wu = (const unsigned short*)upw;
        const unsigned short* Wd = (const unsigned short*)downw;
        gemm_bt<1, 1, 1, 0><<<dim3(32, 48), 256, 0, stream>>>(
            flag, h, Wq, 0, 2048, nullptr, qkv, 6144, 2048);
        attn_kernel<1><<<1024, 256, 0, stream>>>(flag, qkv, o);
        gemm_bt<1, 1, 1, 1><<<dim3(32, 16), 256, 0, stream>>>(
            flag, o, Wo, 0, 2048, x, x2, 2048, 2048);
        rmsnorm_kernel<1, 1, 1><<<4096, 256, 0, stream>>>(flag, x2, n2w, h2);
        gemm_bt<1, 1, 1, 2><<<dim3(32, 32), 256, 0, stream>>>(
            flag, h2, Wg, 0, 2048, nullptr, a, 4096, 2048);
        gemm_bt<1, 1, 1, 3><<<dim3(32, 32), 256, 0, stream>>>(
            flag, h2, Wu, 0, 2048, a, a, 4096, 2048);
        gemm_bt<1, 1, 1, 1><<<dim3(32, 16), 256, 0, stream>>>(
            flag, a, Wd, 0, 8192, x2, x2, 2048, 4096);
        gemm_bt<1, 1, 1, 2><<<dim3(32, 32), 256, 0, stream>>>(
            flag, h2, Wg, (size_t)4096 * 2048, 2048, nullptr, a, 4096, 2048);
        gemm_bt<1, 1, 1, 3><<<dim3(32, 32), 256, 0, stream>>>(
            flag, h2, Wu, (size_t)4096 * 2048, 2048, a, a, 4096, 2048);
        gemm_bt<1, 1, 1, 1><<<dim3(32, 16), 256, 0, stream>>>(
            flag, a, Wd, 4096, 8192, x2, outp, 2048, 4096);
    } else {
        // DT=0: pre-convert each f32 weight panel to bf16, then bf16 GEMMs.
        unsigned short* WC  = (unsigned short*)outp;   // scratch until final
        unsigned short* WC2 = h2;                      // last chunk scratch

        convw_kernel<0><<<6144, 256, 0, stream>>>(
            flag, (const float*)qkvw, 2048, WC, 2048, 6144 * 2048);
        gemm_bt<0, 1, 1, 0><<<dim3(32, 48), 256, 0, stream>>>(
            flag, h, WC, 0, 2048, nullptr, qkv, 6144, 2048);
        attn_kernel<0><<<1024, 256, 0, stream>>>(flag, qkv, o);
        convw_kernel<0><<<2048, 256, 0, stream>>>(
            flag, (const float*)outw, 2048, WC, 2048, 2048 * 2048);
        gemm_bt<0, 0, 1, 1><<<dim3(32, 16), 256, 0, stream>>>(
            flag, o, WC, 0, 2048, x, x2, 2048, 2048);
        rmsnorm_kernel<0, 1, 0><<<4096, 256, 0, stream>>>(flag, x2, n2w, h2);
        // FF chunk 0
        convw_kernel<0><<<4096, 256, 0, stream>>>(
            flag, (const float*)gatew, 2048, WC, 2048, 4096 * 2048);
        gemm_bt<0, 1, 1, 2><<<dim3(32, 32), 256, 0, stream>>>(
            flag, h2, WC, 0, 2048, nullptr, a, 4096, 2048);
        convw_kernel<0><<<4096, 256, 0, stream>>>(
            flag, (const float*)upw, 2048, WC, 2048, 4096 * 2048);
        gemm_bt<0, 1, 1, 3><<<dim3(32, 32), 256, 0, stream>>>(
            flag, h2, WC, 0, 2048, a, a, 4096, 2048);
        convw_kernel<0><<<4096, 256, 0, stream>>>(
            flag, (const float*)downw, 8192, WC, 4096, 2048 * 4096);
        gemm_bt<0, 1, 1, 1><<<dim3(32, 16), 256, 0, stream>>>(
            flag, a, WC, 0, 4096, x2, x2, 2048, 4096);
        // FF chunk 1
        convw_kernel<0><<<4096, 256, 0, stream>>>(
            flag, (const float*)gatew + (size_t)4096 * 2048, 2048, WC, 2048, 4096 * 2048);
        gemm_bt<0, 1, 1, 2><<<dim3(32, 32), 256, 0, stream>>>(
            flag, h2, WC, 0, 2048, nullptr, a, 4096, 2048);
        convw_kernel<0><<<4096, 256, 0, stream>>>(
            flag, (const float*)upw + (size_t)4096 * 2048, 2048, WC, 2048, 4096 * 2048);
        gemm_bt<0, 1, 1, 3><<<dim3(32, 32), 256, 0, stream>>>(
            flag, h2, WC, 0, 2048, a, a, 4096, 2048);
        // last down chunk: conv into h2 region (dead), write f32 to d_out
        convw_kernel<0><<<4096, 256, 0, stream>>>(
            flag, (const float*)downw + 4096, 8192, WC2, 4096, 2048 * 4096);
        gemm_bt<0, 1, 0, 1><<<dim3(32, 16), 256, 0, stream>>>(
            flag, a, WC2, 0, 4096, x2, outp, 2048, 4096);
    }
}

extern "C" void kernel_launch(void* const* d_in, const int* in_sizes, int n_in,
                              void* d_out, int out_size, void* d_ws, size_t ws_size,
                              hipStream_t stream)
{
    const void* x      = d_in[0];
    // d_in[1] = causal mask: implemented analytically, unused
    const void* n1w    = d_in[2];
    const void* qkv_w  = d_in[3];
    const void* out_w  = d_in[4];
    const void* n2w    = d_in[5];
    const void* gate_w = d_in[6];
    const void* up_w   = d_in[7];
    const void* down_w = d_in[8];

    char* ws = (char*)d_ws;
    const size_t MB = 1024 * 1024;
    size_t flag_off = 64 * MB;
    if (ws_size < flag_off + 4) flag_off = (ws_size - 4) & ~(size_t)3;
    int* flag = (int*)(ws + flag_off);

    detect_kernel<<<1, 256, 0, stream>>>((const unsigned int*)x, flag);
    run_pipeline<0>(x, n1w, qkv_w, out_w, n2w, gate_w, up_w, down_w,
                    d_out, ws, flag, stream);
    run_pipeline<1>(x, n1w, qkv_w, out_w, n2w, gate_w, up_w, down_w,
                    d_out, ws, flag, stream);
}